// Round 7
// baseline (218.723 us; speedup 1.0000x reference)
//
#include <hip/hip_runtime.h>
#include <cstddef>

// Problem constants
constexpr int Bn  = 16;    // batch
constexpr int CIc = 32;    // in channels
constexpr int COc = 32;    // out channels
constexpr int Kc  = 16;    // kernel width
constexpr int IN  = 8192;  // input length
constexpr int OUTL = 8176; // output length = IN - K

// Tiling
constexpr int O_B  = 16;   // o-positions per block (8176/16 = 511 exact)
constexpr int CCH  = 8;    // channels staged per chunk
constexpr int NPOS = 32;   // staged x positions (max row = ob+18 = 30 <= 31; o0+31 <= 8191 in bounds)
constexpr int BST  = 20;   // row stride (floats): multiple of 4 (b128 align); reads 2-way conflicted = free
constexpr int NCHUNK = CIc / CCH;  // 4

__global__ __launch_bounds__(256, 2)
void conv1d_cppn_kernel(const float* __restrict__ x, const float* __restrict__ w,
                        const float* __restrict__ bias, float* __restrict__ out) {
    // x transposed: xs[cc][pos][b]  (8*32*20*4 = 20,480 B)
    __shared__ float xs[CCH][NPOS][BST];

    const int tid = threadIdx.x;
    const int bg  = tid & 3;          // b quad: b in [bg*4, bg*4+4)
    const int op  = (tid >> 2) & 3;   // o quad: o in [ob, ob+4)
    const int dg  = tid >> 4;         // 16 d-groups x 2 d = all 32 d
    const int o0 = blockIdx.x * O_B;
    const int ob = op * 4;
    const int o  = o0 + ob;
    const int dbase = dg * 2;
    const int bb = bg * 4;

    // Staging decomposition (float4 over p): thread -> (sp4, sb), channels cl0+2q
    const int sp4 = tid & 7;
    const int sb  = (tid >> 3) & 15;
    const int cl0 = tid >> 7;

    // acc[jd][oo][j]: 2 d x 4 o x 4 b = 32 regs (round-2-proven accumulator budget)
    float acc[2][4][4];
#pragma unroll
    for (int i = 0; i < 2; ++i)
#pragma unroll
        for (int j = 0; j < 4; ++j)
#pragma unroll
            for (int q = 0; q < 4; ++q) acc[i][j][q] = 0.f;

    for (int chunk = 0; chunk < NCHUNK; ++chunk) {
        const int c0 = chunk * CCH;
        __syncthreads();
        // Stage x[b, c0..c0+8, o0..o0+32) transposed. 4 float4 loads/thread.
#pragma unroll
        for (int q = 0; q < 4; ++q) {
            const int cl = cl0 + 2 * q;
            const float4 v = *reinterpret_cast<const float4*>(
                &x[((size_t)sb * CIc + (c0 + cl)) * IN + o0 + sp4 * 4]);
            float (*prow)[BST] = &xs[cl][sp4 * 4];
            prow[0][sb] = v.x; prow[1][sb] = v.y; prow[2][sb] = v.z; prow[3][sb] = v.w;
        }
        __syncthreads();

#pragma unroll 2
        for (int cc = 0; cc < CCH; ++cc) {
            const int c = c0 + cc;
#pragma unroll
            for (int half = 0; half < 2; ++half) {
                // Batch-load the 11 x rows this half needs: independent b128s,
                // deep prefetch possible (round-6 lesson: never serialize LDS reads).
                float rowf[11][4];
#pragma unroll
                for (int r = 0; r < 11; ++r) {
                    const float4 v = *reinterpret_cast<const float4*>(
                        &xs[cc][ob + half * 8 + r][bb]);
                    rowf[r][0] = v.x; rowf[r][1] = v.y; rowf[r][2] = v.z; rowf[r][3] = v.w;
                }
#pragma unroll
                for (int q = 0; q < 2; ++q) {
                    // w taps (half*8 + q*4 ..+4) for 2d x 4o: 32 live w regs
                    float wqf[2][4][4];
#pragma unroll
                    for (int jd = 0; jd < 2; ++jd)
#pragma unroll
                        for (int oo = 0; oo < 4; ++oo) {
                            const float4 v = *reinterpret_cast<const float4*>(
                                &w[(((size_t)(dbase + jd) * CIc + c) * OUTL + (o + oo)) * Kc
                                   + half * 8 + q * 4]);
                            wqf[jd][oo][0] = v.x; wqf[jd][oo][1] = v.y;
                            wqf[jd][oo][2] = v.z; wqf[jd][oo][3] = v.w;
                        }
#pragma unroll
                    for (int kk = 0; kk < 4; ++kk) {
                        const int lr = q * 4 + kk;   // local row base; lr+oo <= 10
#pragma unroll
                        for (int jd = 0; jd < 2; ++jd)
#pragma unroll
                            for (int oo = 0; oo < 4; ++oo) {
                                const float wk = wqf[jd][oo][kk];
#pragma unroll
                                for (int j = 0; j < 4; ++j)
                                    acc[jd][oo][j] += wk * rowf[lr + oo][j];
                            }
                    }
                }
            }
        }
    }

    // Epilogue: bias + relu; float4 over the o-quad (full 64B-line coalescing:
    // the 4 op-lanes of each (bg,dg) cover one contiguous 64B out line).
#pragma unroll
    for (int jd = 0; jd < 2; ++jd) {
        const float bv = bias[dbase + jd];
#pragma unroll
        for (int j = 0; j < 4; ++j) {
            float4 st;
            float v0 = acc[jd][0][j] + bv;
            float v1 = acc[jd][1][j] + bv;
            float v2 = acc[jd][2][j] + bv;
            float v3 = acc[jd][3][j] + bv;
            st.x = v0 > 0.f ? v0 : 0.f;
            st.y = v1 > 0.f ? v1 : 0.f;
            st.z = v2 > 0.f ? v2 : 0.f;
            st.w = v3 > 0.f ? v3 : 0.f;
            *reinterpret_cast<float4*>(
                &out[((size_t)(bb + j) * COc + (dbase + jd)) * OUTL + o]) = st;
        }
    }
}

extern "C" void kernel_launch(void* const* d_in, const int* in_sizes, int n_in,
                              void* d_out, int out_size, void* d_ws, size_t ws_size,
                              hipStream_t stream) {
    const float* x    = (const float*)d_in[0];
    const float* w    = (const float*)d_in[1];
    const float* bias = (const float*)d_in[2];
    float* out        = (float*)d_out;

    dim3 grid(OUTL / O_B);  // 511
    dim3 block(256);
    hipLaunchKernelGGL(conv1d_cppn_kernel, grid, block, 0, stream, x, w, bias, out);
}

// Round 8
// 192.753 us; speedup vs baseline: 1.1347x; 1.1347x over previous
//
#include <hip/hip_runtime.h>
#include <cstddef>

// Problem constants
constexpr int Bn  = 16;    // batch
constexpr int CIc = 32;    // in channels
constexpr int COc = 32;    // out channels
constexpr int Kc  = 16;    // kernel width
constexpr int IN  = 8192;  // input length
constexpr int OUTL = 8176; // output length = IN - K

// Tiling
constexpr int O_B  = 8;    // o-positions per block (8176/8 = 1022 exact)
constexpr int CCH  = 8;    // channels per cg-half per chunk
constexpr int NPOS = 32;   // staged positions; start clamped so s0+31 <= 8191
constexpr int BST  = 20;   // row stride: 8-row read pattern covers all 32 banks once (conflict-free)

// xs[2cg][8cc][32p][20b] = 10240 floats (40,960 B); red aliased on top
constexpr int SMEM_FLOATS = 2 * CCH * NPOS * BST;

__global__ __launch_bounds__(256, 2)
void conv1d_cppn_kernel(const float* __restrict__ x, const float* __restrict__ w,
                        const float* __restrict__ bias, float* __restrict__ out) {
    __shared__ float smem[SMEM_FLOATS];
    float (*xs)[CCH][NPOS][BST] = reinterpret_cast<float (*)[CCH][NPOS][BST]>(smem);
    float (*red)[16][O_B][18]   = reinterpret_cast<float (*)[16][O_B][18]>(smem); // [jd][dg][og][b-pad]

    const int tid = threadIdx.x;
    const int og = tid & 7;           // o within tile
    const int dg = (tid >> 3) & 15;   // 16 d-groups x 2 d = all 32 d
    const int cg = tid >> 7;          // c-half: cg0 -> c 0..15, cg1 -> c 16..31 (disjoint w => fetch-once)
    const int o0 = blockIdx.x * O_B;
    const int o  = o0 + og;
    const int dbase = dg * 2;

    // Clamp staging window so global reads stay in bounds (last block: o0=8168)
    const int s0 = (o0 > IN - NPOS) ? (IN - NPOS) : o0;
    const int d0 = o0 - s0;           // 0 except last block (=8); read rows og+d0+k <= 30

    // Staging decomposition (identical shape to round 2): (sp4, sb), channels cl0+2q
    const int sp4 = tid & 7;
    const int sb  = (tid >> 3) & 15;
    const int cl0 = tid >> 7;

    // ===== round-2-proven register shape: DO NOT ALTER =====
    float acc[2][16];
#pragma unroll
    for (int i = 0; i < 2; ++i)
#pragma unroll
        for (int j = 0; j < 16; ++j) acc[i][j] = 0.f;

    for (int chunk = 0; chunk < 2; ++chunk) {
        __syncthreads();
        // Stage 16 channels (8 per cg-half): 8 float4 loads/thread, coalesced over p.
#pragma unroll
        for (int q = 0; q < 8; ++q) {
            const int cl = cl0 + 2 * q;   // 0..15
            const float4 v = *reinterpret_cast<const float4*>(
                &x[((size_t)sb * CIc + (chunk * 16 + cl)) * IN + s0 + sp4 * 4]);
            float (*prow)[BST] = &xs[cl >> 3][cl & 7][sp4 * 4];
            prow[0][sb] = v.x; prow[1][sb] = v.y; prow[2][sb] = v.z; prow[3][sb] = v.w;
        }
        __syncthreads();

#pragma unroll 2   // round-2 proven: bounded unroll
        for (int cc = 0; cc < CCH; ++cc) {
            const int c = chunk * 16 + cg * 8 + cc;
            float wreg[2][16];
#pragma unroll
            for (int jd = 0; jd < 2; ++jd) {
                const float4* wp = reinterpret_cast<const float4*>(
                    w + (((size_t)(dbase + jd) * CIc + c) * OUTL + o) * Kc);
#pragma unroll
                for (int q = 0; q < 4; ++q) {
                    const float4 v = wp[q];
                    wreg[jd][q * 4 + 0] = v.x;
                    wreg[jd][q * 4 + 1] = v.y;
                    wreg[jd][q * 4 + 2] = v.z;
                    wreg[jd][q * 4 + 3] = v.w;
                }
            }
#pragma unroll
            for (int k = 0; k < Kc; ++k) {
                const float* xrow = &xs[cg][cc][og + d0 + k][0];
                float xv[16];
                *reinterpret_cast<float4*>(&xv[0])  = *reinterpret_cast<const float4*>(xrow);
                *reinterpret_cast<float4*>(&xv[4])  = *reinterpret_cast<const float4*>(xrow + 4);
                *reinterpret_cast<float4*>(&xv[8])  = *reinterpret_cast<const float4*>(xrow + 8);
                *reinterpret_cast<float4*>(&xv[12]) = *reinterpret_cast<const float4*>(xrow + 12);
#pragma unroll
                for (int jd = 0; jd < 2; ++jd) {
                    const float wk = wreg[jd][k];
#pragma unroll
                    for (int jb = 0; jb < 16; ++jb) {
                        acc[jd][jb] += wk * xv[jb];
                    }
                }
            }
        }
    }
    // ===== end protected inner loop =====

    // Combine cg partials via aliased LDS (xs dead after barrier), float2 granularity.
    __syncthreads();
    if (cg == 1) {
#pragma unroll
        for (int jd = 0; jd < 2; ++jd) {
            float* row = &red[jd][dg][og][0];
#pragma unroll
            for (int s = 0; s < 8; ++s) {
                *reinterpret_cast<float2*>(row + s * 2) =
                    make_float2(acc[jd][s * 2], acc[jd][s * 2 + 1]);
            }
        }
    }
    __syncthreads();
    if (cg == 0) {
#pragma unroll
        for (int jd = 0; jd < 2; ++jd) {
            const float bv = bias[dbase + jd];
            const float* row = &red[jd][dg][og][0];
#pragma unroll
            for (int jb = 0; jb < 16; ++jb) {
                float v = acc[jd][jb] + row[jb] + bv;
                out[((size_t)jb * COc + (dbase + jd)) * OUTL + o] = v > 0.f ? v : 0.f;
            }
        }
    }
}

extern "C" void kernel_launch(void* const* d_in, const int* in_sizes, int n_in,
                              void* d_out, int out_size, void* d_ws, size_t ws_size,
                              hipStream_t stream) {
    const float* x    = (const float*)d_in[0];
    const float* w    = (const float*)d_in[1];
    const float* bias = (const float*)d_in[2];
    float* out        = (float*)d_out;

    dim3 grid(OUTL / O_B);  // 1022
    dim3 block(256);
    hipLaunchKernelGGL(conv1d_cppn_kernel, grid, block, 0, stream, x, w, bias, out);
}

// Round 9
// 137.281 us; speedup vs baseline: 1.5933x; 1.4041x over previous
//
#include <hip/hip_runtime.h>
#include <cstddef>

// Problem constants
constexpr int Bn  = 16;    // batch
constexpr int CIc = 32;    // in channels
constexpr int COc = 32;    // out channels
constexpr int Kc  = 16;    // kernel width
constexpr int IN  = 8192;  // input length
constexpr int OUTL = 8176; // output length = IN - K

// Tiling
constexpr int O_B  = 16;   // o-positions per block (8176/16 = 511 exact)
constexpr int CCH  = 8;    // channels staged per chunk
constexpr int NPOS = 32;   // staged positions (o0+31 <= 8191 in bounds)
constexpr int BST  = 20;   // row stride in floats (b128-aligned; with parity-deinterleave reads are 2-way = free)
constexpr int NCHUNK = CIc / CCH;  // 4

// Rows stored parity-deinterleaved: logical pos p -> physical row (p>>1) + (p&1)*16.
// Read pattern (8 ogp-lanes, stride 1 physical row = 20 words): bank starts
// {0,20,8,28,16,4,24,12} + bg*8 -> every bank hit exactly 2x = free (m136).

__global__ __launch_bounds__(256, 2)
void conv1d_cppn_kernel(const float* __restrict__ x, const float* __restrict__ w,
                        const float* __restrict__ bias, float* __restrict__ out) {
    __shared__ float xs[CCH][NPOS][BST];   // 20,480 B

    const int tid = threadIdx.x;
    const int bg  = tid & 1;           // batch half: b in [bg*8, bg*8+8)
    const int ogp = (tid >> 1) & 7;    // o-pair: owns o, o+1
    const int dg  = tid >> 4;          // 16 d-groups x 2 d = all 32 d
    const int o0 = blockIdx.x * O_B;
    const int ob = ogp * 2;
    const int o  = o0 + ob;
    const int dbase = dg * 2;
    const int bb = bg * 8;

    // Staging decomposition (round-2 shape): (sp4, sb), channels cl0+2q
    const int sp4 = tid & 7;
    const int sb  = (tid >> 3) & 15;
    const int cl0 = tid >> 7;

    // acc: 2 d x 2 o x 8 b = 32 regs (proven budget)
    float acc[2][2][8];
#pragma unroll
    for (int i = 0; i < 2; ++i)
#pragma unroll
        for (int j = 0; j < 2; ++j)
#pragma unroll
            for (int q = 0; q < 8; ++q) acc[i][j][q] = 0.f;

    for (int chunk = 0; chunk < NCHUNK; ++chunk) {
        const int c0 = chunk * CCH;
        __syncthreads();
        // Stage x transposed + parity-deinterleaved. 4 float4 loads/thread.
#pragma unroll
        for (int q = 0; q < 4; ++q) {
            const int cl = cl0 + 2 * q;
            const float4 v = *reinterpret_cast<const float4*>(
                &x[((size_t)sb * CIc + (c0 + cl)) * IN + o0 + sp4 * 4]);
            // positions 4*sp4 .. 4*sp4+3 -> phys rows 2sp4, 2sp4+16, 2sp4+1, 2sp4+17
            xs[cl][sp4 * 2 + 0 ][sb] = v.x;
            xs[cl][sp4 * 2 + 16][sb] = v.y;
            xs[cl][sp4 * 2 + 1 ][sb] = v.z;
            xs[cl][sp4 * 2 + 17][sb] = v.w;
        }
        __syncthreads();

#pragma unroll 1   // exactly one cc's w batch in flight (rounds 3/4/7 lesson)
        for (int cc = 0; cc < CCH; ++cc) {
            const int c = c0 + cc;
            // RULE: all w for this cc up-front, one independent batch (16 float4).
            float wreg[2][2][16];
#pragma unroll
            for (int jd = 0; jd < 2; ++jd)
#pragma unroll
                for (int oo = 0; oo < 2; ++oo) {
                    const float4* wp = reinterpret_cast<const float4*>(
                        w + (((size_t)(dbase + jd) * CIc + c) * OUTL + (o + oo)) * Kc);
#pragma unroll
                    for (int q = 0; q < 4; ++q) {
                        const float4 v = wp[q];
                        wreg[jd][oo][q * 4 + 0] = v.x;
                        wreg[jd][oo][q * 4 + 1] = v.y;
                        wreg[jd][oo][q * 4 + 2] = v.z;
                        wreg[jd][oo][q * 4 + 3] = v.w;
                    }
                }

#pragma unroll
            for (int h = 0; h < 2; ++h) {
                // Batched, independent LDS reads: 9 rows x 2 b128.
                // Logical rows ob+8h+lr ; even lr -> phys ogp+4h+(lr>>1),
                // odd lr -> phys 16+ogp+4h+(lr>>1). All offsets compile-time.
                float xr[9][8];
                const int eb = ogp + 4 * h;        // even-row phys base
                const int obs = 16 + ogp + 4 * h;  // odd-row phys base
#pragma unroll
                for (int lr = 0; lr < 9; ++lr) {
                    const int pr = (lr & 1) ? (obs + (lr >> 1)) : (eb + (lr >> 1));
                    const float* src = &xs[cc][pr][bb];
                    *reinterpret_cast<float4*>(&xr[lr][0]) = *reinterpret_cast<const float4*>(src);
                    *reinterpret_cast<float4*>(&xr[lr][4]) = *reinterpret_cast<const float4*>(src + 4);
                }
#pragma unroll
                for (int kk = 0; kk < 8; ++kk) {
#pragma unroll
                    for (int jd = 0; jd < 2; ++jd)
#pragma unroll
                        for (int oo = 0; oo < 2; ++oo) {
                            const float wk = wreg[jd][oo][h * 8 + kk];
                            const float* xv = &xr[kk + oo][0];
#pragma unroll
                            for (int j = 0; j < 8; ++j)
                                acc[jd][oo][j] += wk * xv[j];
                        }
                }
            }
        }
    }

    // Epilogue: bias + relu; float2 over (o, o+1), lanes dense over ogp.
#pragma unroll
    for (int jd = 0; jd < 2; ++jd) {
        const float bv = bias[dbase + jd];
#pragma unroll
        for (int j = 0; j < 8; ++j) {
            float v0 = acc[jd][0][j] + bv;
            float v1 = acc[jd][1][j] + bv;
            float2 st = make_float2(v0 > 0.f ? v0 : 0.f, v1 > 0.f ? v1 : 0.f);
            *reinterpret_cast<float2*>(
                &out[((size_t)(bb + j) * COc + (dbase + jd)) * OUTL + o]) = st;
        }
    }
}

extern "C" void kernel_launch(void* const* d_in, const int* in_sizes, int n_in,
                              void* d_out, int out_size, void* d_ws, size_t ws_size,
                              hipStream_t stream) {
    const float* x    = (const float*)d_in[0];
    const float* w    = (const float*)d_in[1];
    const float* bias = (const float*)d_in[2];
    float* out        = (float*)d_out;

    dim3 grid(OUTL / O_B);  // 511
    dim3 block(256);
    hipLaunchKernelGGL(conv1d_cppn_kernel, grid, block, 0, stream, x, w, bias, out);
}